// Round 13
// baseline (318.989 us; speedup 1.0000x reference)
//
#include <hip/hip_runtime.h>
#include <hip/hip_bf16.h>

#define N_NODES 50000
#define N_EDGES 800000
#define ET_EDGES 850000   // + self loops
#define HEADS 4
#define NG64 782          // ceil(N_NODES/64)
#define ENC_BLOCKS 1563   // ceil(N_NODES/32)

// bucketed CSR build
#define BSHIFT 8
#define NBUK 196          // ceil(50000/256)
#define BCAP 6144         // max edges/bucket
#define EB_PER_BLOCK 4096
#define EB_BLOCKS 208     // 208*4096 >= 850000

__device__ __forceinline__ float lrelu(float v) { return v > 0.f ? v : 0.2f * v; }

// bf16 round-to-nearest-even pack/unpack
__device__ __forceinline__ unsigned short f2bf(float f) {
    unsigned int u = __float_as_uint(f);
    u = (u + 0x7FFFu + ((u >> 16) & 1u)) >> 16;
    return (unsigned short)u;
}
__device__ __forceinline__ float bf2f(unsigned short h) {
    return __uint_as_float((unsigned int)h << 16);
}

__device__ __forceinline__ void edge_sd(const int* __restrict__ ei, int e, int& s, int& d) {
    if (e < N_EDGES) { s = ei[e]; d = ei[N_EDGES + e]; }
    else { s = d = e - N_EDGES; }
}

// ---------------- zero bucket cursors + fold attention vectors ----------------
__global__ __launch_bounds__(256) void zerofold_kernel(
    int* __restrict__ bcur,
    const float* __restrict__ g1w, const float* __restrict__ g1as, const float* __restrict__ g1ad,
    float* __restrict__ wsf, float* __restrict__ wdf) {
    if (blockIdx.x == 0) {
        if (threadIdx.x < NBUK) bcur[threadIdx.x] = 0;
    } else {
        int tid = threadIdx.x;       // tid = h*64+k
        int h = tid >> 6, k = tid & 63;
        float as_acc = 0.f, ad_acc = 0.f;
        #pragma unroll 8
        for (int c = 0; c < 64; ++c) {
            float w = g1w[k * 256 + h * 64 + c];
            as_acc += w * g1as[h * 64 + c];
            ad_acc += w * g1ad[h * 64 + c];
        }
        wsf[tid] = as_acc;
        wdf[tid] = ad_acc;
    }
}

// ---------------- mega: bucket-scatter edges (blocks 0..EB) + encoder/alpha1 (rest) ----------------
__global__ __launch_bounds__(256) void mega_kernel(
    const int* __restrict__ ei, int* __restrict__ bcur, int* __restrict__ ebuf,
    const float* __restrict__ x, const float* __restrict__ w1, const float* __restrict__ b1,
    const float* __restrict__ w2, const float* __restrict__ b2,
    const float* __restrict__ wsf, const float* __restrict__ wdf,
    unsigned short* __restrict__ henc, float* __restrict__ as1, float* __restrict__ ad1) {
    __shared__ union {
        struct { int es[EB_PER_BLOCK]; int ed[EB_PER_BLOCK]; int h[NBUK]; int base[NBUK]; } buk;
        struct { float w2[4096]; float t[32][64]; float xx[32][8]; float he[32][65]; float wf[8 * 65]; } enc;
    } u;
    int tid = threadIdx.x;
    if (blockIdx.x < EB_BLOCKS) {
        for (int i = tid; i < NBUK; i += 256) u.buk.h[i] = 0;
        int e0 = blockIdx.x * EB_PER_BLOCK;
        __syncthreads();
        #pragma unroll
        for (int r = 0; r < EB_PER_BLOCK / 256; ++r) {
            int i = r * 256 + tid;
            int e = e0 + i;
            if (e < ET_EDGES) {
                int s, d; edge_sd(ei, e, s, d);
                u.buk.es[i] = s;
                u.buk.ed[i] = d;
                atomicAdd(&u.buk.h[d >> BSHIFT], 1);
            } else {
                u.buk.ed[i] = -1;
            }
        }
        __syncthreads();
        for (int i = tid; i < NBUK; i += 256) {
            int c = u.buk.h[i];
            u.buk.base[i] = c ? atomicAdd(bcur + i, c) : 0;
            u.buk.h[i] = 0;   // reuse as cursor
        }
        __syncthreads();
        #pragma unroll
        for (int r = 0; r < EB_PER_BLOCK / 256; ++r) {
            int i = r * 256 + tid;
            int d = u.buk.ed[i];
            if (d >= 0) {
                int b = d >> BSHIFT;
                int off = atomicAdd(&u.buk.h[b], 1);
                ebuf[b * BCAP + u.buk.base[b] + off] = ((d & 255) << 16) | u.buk.es[i];
            }
        }
        return;
    }
    // ---- encoder + fused alpha1 (32 nodes/block) ----
    int node0 = (blockIdx.x - EB_BLOCKS) * 32;
    for (int i = tid; i < 4096; i += 256) u.enc.w2[i] = w2[i];
    for (int i = tid; i < 224; i += 256) {
        int src = node0 * 7 + i;
        u.enc.xx[i / 7][i % 7] = (src < N_NODES * 7) ? x[src] : 0.f;
    }
    for (int i = tid; i < 512; i += 256) {
        int g = i >> 6, k = i & 63;
        int h = g & 3;
        u.enc.wf[g * 65 + k] = (g < 4) ? wsf[h * 64 + k] : wdf[h * 64 + k];
    }
    int c = tid & 63;
    int mg = tid >> 6;
    float w1c[7];
    #pragma unroll
    for (int k = 0; k < 7; ++k) w1c[k] = w1[k * 64 + c];
    float b1c = b1[c];
    __syncthreads();
    #pragma unroll
    for (int m = 0; m < 8; ++m) {
        int nn = mg * 8 + m;
        float a = b1c;
        #pragma unroll
        for (int k = 0; k < 7; ++k) a += u.enc.xx[nn][k] * w1c[k];
        u.enc.t[nn][c] = fmaxf(a, 0.f);
    }
    __syncthreads();
    float acc[8];
    float b2c = b2[c];
    #pragma unroll
    for (int m = 0; m < 8; ++m) acc[m] = b2c;
    #pragma unroll 4
    for (int k = 0; k < 64; ++k) {
        float w = u.enc.w2[k * 64 + c];
        #pragma unroll
        for (int m = 0; m < 8; ++m) acc[m] += u.enc.t[mg * 8 + m][k] * w;
    }
    #pragma unroll
    for (int m = 0; m < 8; ++m) {
        int nn = mg * 8 + m;
        int node = node0 + nn;
        u.enc.he[nn][c] = acc[m];
        if (node < N_NODES) henc[node * 64 + c] = f2bf(acc[m]);
    }
    __syncthreads();
    {
        int nn = tid >> 3, r = tid & 7;
        int node = node0 + nn;
        const float* wf = u.enc.wf + r * 65;
        float sum = 0.f;
        #pragma unroll 8
        for (int k = 0; k < 64; ++k) sum += u.enc.he[nn][k] * wf[k];
        if (node < N_NODES) {
            int hh = r & 3;
            if (r < 4) as1[node * 4 + hh] = sum;
            else       ad1[node * 4 + hh] = sum;
        }
    }
}

// ---------------- per-bucket CSR finalize: 1 block = 256-node bucket ----------------
__global__ __launch_bounds__(256) void bucket_csr_kernel(
    const int* __restrict__ ebuf, const int* __restrict__ bcur,
    int* __restrict__ rowbeg, int* __restrict__ degarr, int* __restrict__ csr_src) {
    __shared__ int s_deg[256];
    __shared__ int s_cur[256];
    __shared__ int s_w[4];
    int b = blockIdx.x;
    int tid = threadIdx.x;
    s_deg[tid] = 0;
    int cnt = bcur[b];
    int base = b * BCAP;
    const int* eb = ebuf + base;
    int node0 = b << BSHIFT;
    __syncthreads();
    for (int i = tid; i < cnt; i += 256) atomicAdd(&s_deg[eb[i] >> 16], 1);
    __syncthreads();
    int v = s_deg[tid];
    int lane = tid & 63, w = tid >> 6;
    int xv = v;
    #pragma unroll
    for (int off = 1; off < 64; off <<= 1) {
        int t = __shfl_up(xv, off);
        if (lane >= off) xv += t;
    }
    if (lane == 63) s_w[w] = xv;
    __syncthreads();
    if (tid == 0) {
        int a = 0;
        #pragma unroll
        for (int j = 0; j < 4; ++j) { int t = s_w[j]; s_w[j] = a; a += t; }
    }
    __syncthreads();
    int excl = xv - v + s_w[w];
    s_cur[tid] = excl;
    int node = node0 + tid;
    if (node < N_NODES) {
        rowbeg[node] = base + excl;
        degarr[node] = v;
    }
    __syncthreads();
    for (int i = tid; i < cnt; i += 256) {
        int p = eb[i];
        int pos = atomicAdd(&s_cur[p >> 16], 1);
        csr_src[base + pos] = p & 0xFFFF;
    }
}

// ---------------- GAT1 aggregate: dual-edge bf16 gather, bf16 planar out ----------------
// half-wave (32 lanes x 2ch) per edge; wave does 2 edges/iter. agg[h][n][k] bf16.
__global__ __launch_bounds__(256) void aggregate1_kernel(
    const int* __restrict__ rowbeg, const int* __restrict__ degarr, const int* __restrict__ csr_src,
    const float* __restrict__ as, const float* __restrict__ ad,
    const unsigned short* __restrict__ henc, unsigned short* __restrict__ agg) {
    int wslot = threadIdx.x >> 6;
    int lane  = threadIdx.x & 63;
    int half  = lane >> 5;
    int c2    = (lane & 31) * 2;
    int n = blockIdx.x * 4 + wslot;
    __shared__ int    ls[4][64];
    __shared__ float4 lp4[4][64];
    if (n >= N_NODES) return;
    int base = rowbeg[n];
    int deg  = degarr[n];
    float4 add = *(const float4*)(ad + n * 4);

    float4 l = make_float4(0.f, 0.f, 0.f, 0.f);
    float ax0 = 0.f, ax1 = 0.f, ay0 = 0.f, ay1 = 0.f;
    float az0 = 0.f, az1 = 0.f, aw0 = 0.f, aw1 = 0.f;
    for (int c0 = 0; c0 < deg; c0 += 64) {
        int j = c0 + lane;
        int s = 0;
        float4 p = make_float4(0.f, 0.f, 0.f, 0.f);
        if (j < deg) {
            s = csr_src[base + j];
            float4 a = *(const float4*)(as + s * 4);
            p.x = __expf(lrelu(a.x + add.x));
            p.y = __expf(lrelu(a.y + add.y));
            p.z = __expf(lrelu(a.z + add.z));
            p.w = __expf(lrelu(a.w + add.w));
        }
        ls[wslot][lane] = s;
        lp4[wslot][lane] = p;
        float4 t = p;
        #pragma unroll
        for (int off = 32; off > 0; off >>= 1) {
            t.x += __shfl_xor(t.x, off);
            t.y += __shfl_xor(t.y, off);
            t.z += __shfl_xor(t.z, off);
            t.w += __shfl_xor(t.w, off);
        }
        l.x += t.x; l.y += t.y; l.z += t.z; l.w += t.w;
        int cnt = min(64, deg - c0);
        const int*    lsw = ls[wslot];
        const float4* lpw = lp4[wslot];
        int j2 = 0;
        for (; j2 + 16 <= cnt; j2 += 16) {
            unsigned int raw[8];
            #pragma unroll
            for (int uu = 0; uu < 8; ++uu) {
                int e = j2 + 2 * uu + half;
                raw[uu] = *(const unsigned int*)(henc + (size_t)lsw[e] * 64 + c2);
            }
            #pragma unroll
            for (int uu = 0; uu < 8; ++uu) {
                float v0 = bf2f((unsigned short)(raw[uu] & 0xFFFFu));
                float v1 = bf2f((unsigned short)(raw[uu] >> 16));
                float4 pj = lpw[j2 + 2 * uu + half];
                ax0 += pj.x * v0; ax1 += pj.x * v1;
                ay0 += pj.y * v0; ay1 += pj.y * v1;
                az0 += pj.z * v0; az1 += pj.z * v1;
                aw0 += pj.w * v0; aw1 += pj.w * v1;
            }
        }
        for (; j2 + 2 <= cnt; j2 += 2) {
            int e = j2 + half;
            unsigned int raw = *(const unsigned int*)(henc + (size_t)lsw[e] * 64 + c2);
            float v0 = bf2f((unsigned short)(raw & 0xFFFFu));
            float v1 = bf2f((unsigned short)(raw >> 16));
            float4 pj = lpw[e];
            ax0 += pj.x * v0; ax1 += pj.x * v1;
            ay0 += pj.y * v0; ay1 += pj.y * v1;
            az0 += pj.z * v0; az1 += pj.z * v1;
            aw0 += pj.w * v0; aw1 += pj.w * v1;
        }
        if (j2 < cnt && half == 0) {
            unsigned int raw = *(const unsigned int*)(henc + (size_t)lsw[j2] * 64 + c2);
            float v0 = bf2f((unsigned short)(raw & 0xFFFFu));
            float v1 = bf2f((unsigned short)(raw >> 16));
            float4 pj = lpw[j2];
            ax0 += pj.x * v0; ax1 += pj.x * v1;
            ay0 += pj.y * v0; ay1 += pj.y * v1;
            az0 += pj.z * v0; az1 += pj.z * v1;
            aw0 += pj.w * v0; aw1 += pj.w * v1;
        }
    }
    // combine even/odd-edge halves
    ax0 += __shfl_xor(ax0, 32); ax1 += __shfl_xor(ax1, 32);
    ay0 += __shfl_xor(ay0, 32); ay1 += __shfl_xor(ay1, 32);
    az0 += __shfl_xor(az0, 32); az1 += __shfl_xor(az1, 32);
    aw0 += __shfl_xor(aw0, 32); aw1 += __shfl_xor(aw1, 32);
    float ix = 1.f / (l.x + 1e-16f), iy = 1.f / (l.y + 1e-16f);
    float iz = 1.f / (l.z + 1e-16f), iw = 1.f / (l.w + 1e-16f);
    size_t o = (size_t)n * 64 + c2;
    const size_t PL = (size_t)N_NODES * 64;
    if (half == 0) {
        ushort2 h0; h0.x = f2bf(ax0 * ix); h0.y = f2bf(ax1 * ix);
        *(ushort2*)(agg + o) = h0;
        ushort2 h1; h1.x = f2bf(ay0 * iy); h1.y = f2bf(ay1 * iy);
        *(ushort2*)(agg + PL + o) = h1;
    } else {
        ushort2 h2v; h2v.x = f2bf(az0 * iz); h2v.y = f2bf(az1 * iz);
        *(ushort2*)(agg + 2 * PL + o) = h2v;
        ushort2 h3; h3.x = f2bf(aw0 * iw); h3.y = f2bf(aw1 * iw);
        *(ushort2*)(agg + 3 * PL + o) = h3;
    }
}

// ---------------- GEMM1: out1(bf16)[n][h*64+q] = ELU(sum_k agg_bf16[h][n][k]*g1w + b) ----------------
__global__ __launch_bounds__(256, 4) void gemm1_kernel(
    const unsigned short* __restrict__ agg, const float* __restrict__ g1w, const float* __restrict__ g1b,
    unsigned short* __restrict__ out1) {
    __shared__ float s_a[64 * 68];   // [n][k], stride 68
    __shared__ float s_w[4096];      // [k][q]
    int tid = threadIdx.x;
    int h = blockIdx.x & 3;
    int node0 = (blockIdx.x >> 2) * 64;
    const unsigned short* aggp = agg + (size_t)h * N_NODES * 64;
    #pragma unroll
    for (int rep = 0; rep < 4; ++rep) {
        int f4 = rep * 256 + tid;            // 0..1023
        int n = f4 >> 4, k4 = (f4 & 15) * 4;
        int node = node0 + n;
        float4 fv = make_float4(0.f, 0.f, 0.f, 0.f);
        if (node < N_NODES) {
            ushort4 rv = *(const ushort4*)(aggp + (size_t)node * 64 + k4);
            fv.x = bf2f(rv.x); fv.y = bf2f(rv.y); fv.z = bf2f(rv.z); fv.w = bf2f(rv.w);
        }
        *(float4*)(s_a + n * 68 + k4) = fv;
        *(float4*)(s_w + f4 * 4) = *(const float4*)(g1w + n * 256 + h * 64 + k4);  // n==k, k4==q4
    }
    __syncthreads();
    int lane = tid & 63, w = tid >> 6;
    int lc = lane & 15, g = lane >> 4;
    int q0 = lc * 4;
    int m0 = (w * 4 + g) * 4;
    float acc[4][4];
    #pragma unroll
    for (int i = 0; i < 4; ++i)
        #pragma unroll
        for (int j = 0; j < 4; ++j) acc[i][j] = 0.f;
    #pragma unroll 4
    for (int k = 0; k < 64; ++k) {
        float4 wv = *(const float4*)(s_w + k * 64 + q0);
        float a0 = s_a[(m0 + 0) * 68 + k];
        float a1 = s_a[(m0 + 1) * 68 + k];
        float a2 = s_a[(m0 + 2) * 68 + k];
        float a3 = s_a[(m0 + 3) * 68 + k];
        acc[0][0] += a0 * wv.x; acc[0][1] += a0 * wv.y; acc[0][2] += a0 * wv.z; acc[0][3] += a0 * wv.w;
        acc[1][0] += a1 * wv.x; acc[1][1] += a1 * wv.y; acc[1][2] += a1 * wv.z; acc[1][3] += a1 * wv.w;
        acc[2][0] += a2 * wv.x; acc[2][1] += a2 * wv.y; acc[2][2] += a2 * wv.z; acc[2][3] += a2 * wv.w;
        acc[3][0] += a3 * wv.x; acc[3][1] += a3 * wv.y; acc[3][2] += a3 * wv.z; acc[3][3] += a3 * wv.w;
    }
    float4 bb = *(const float4*)(g1b + h * 64 + q0);
    #pragma unroll
    for (int i = 0; i < 4; ++i) {
        int node = node0 + m0 + i;
        if (node < N_NODES) {
            float t0 = acc[i][0] + bb.x; t0 = t0 > 0.f ? t0 : expm1f(t0);
            float t1 = acc[i][1] + bb.y; t1 = t1 > 0.f ? t1 : expm1f(t1);
            float t2 = acc[i][2] + bb.z; t2 = t2 > 0.f ? t2 : expm1f(t2);
            float t3 = acc[i][3] + bb.w; t3 = t3 > 0.f ? t3 : expm1f(t3);
            ushort4 ov; ov.x = f2bf(t0); ov.y = f2bf(t1); ov.z = f2bf(t2); ov.w = f2bf(t3);
            *(ushort4*)(out1 + (size_t)node * 256 + h * 64 + q0) = ov;
        }
    }
}

// ---------------- GEMM2: h2(bf16)[n][c] = sum_K out1_bf16[n][K]*g2w[K][c]; + fused alpha2 ----------------
__global__ __launch_bounds__(256, 4) void gemm2_kernel(
    const unsigned short* __restrict__ out1, const float* __restrict__ g2w,
    const float* __restrict__ g2as, const float* __restrict__ g2ad,
    unsigned short* __restrict__ h2, float* __restrict__ as2, float* __restrict__ ad2) {
    __shared__ float s_v[64 * 68];   // [n][kk], stride 68
    __shared__ float s_w[4096];      // [kk][c]
    int tid = threadIdx.x;
    int node0 = blockIdx.x * 64;
    int lane = tid & 63, w = tid >> 6;
    int lc = lane & 15, g = lane >> 4;
    int c0 = lc * 4;
    int m0 = (w * 4 + g) * 4;
    float acc[4][4];
    #pragma unroll
    for (int i = 0; i < 4; ++i)
        #pragma unroll
        for (int j = 0; j < 4; ++j) acc[i][j] = 0.f;
    for (int kc = 0; kc < 4; ++kc) {
        __syncthreads();
        #pragma unroll
        for (int rep = 0; rep < 4; ++rep) {
            int f4 = rep * 256 + tid;
            int n = f4 >> 4, k4 = (f4 & 15) * 4;
            int node = node0 + n;
            float4 fv = make_float4(0.f, 0.f, 0.f, 0.f);
            if (node < N_NODES) {
                ushort4 rv = *(const ushort4*)(out1 + (size_t)node * 256 + kc * 64 + k4);
                fv.x = bf2f(rv.x); fv.y = bf2f(rv.y); fv.z = bf2f(rv.z); fv.w = bf2f(rv.w);
            }
            *(float4*)(s_v + n * 68 + k4) = fv;
            *(float4*)(s_w + f4 * 4) = *(const float4*)(g2w + kc * 4096 + f4 * 4);
        }
        __syncthreads();
        #pragma unroll 4
        for (int kk = 0; kk < 64; ++kk) {
            float4 wv = *(const float4*)(s_w + kk * 64 + c0);
            float a0 = s_v[(m0 + 0) * 68 + kk];
            float a1 = s_v[(m0 + 1) * 68 + kk];
            float a2 = s_v[(m0 + 2) * 68 + kk];
            float a3 = s_v[(m0 + 3) * 68 + kk];
            acc[0][0] += a0 * wv.x; acc[0][1] += a0 * wv.y; acc[0][2] += a0 * wv.z; acc[0][3] += a0 * wv.w;
            acc[1][0] += a1 * wv.x; acc[1][1] += a1 * wv.y; acc[1][2] += a1 * wv.z; acc[1][3] += a1 * wv.w;
            acc[2][0] += a2 * wv.x; acc[2][1] += a2 * wv.y; acc[2][2] += a2 * wv.z; acc[2][3] += a2 * wv.w;
            acc[3][0] += a3 * wv.x; acc[3][1] += a3 * wv.y; acc[3][2] += a3 * wv.z; acc[3][3] += a3 * wv.w;
        }
    }
    float4 ga = *(const float4*)(g2as + c0);
    float4 gd = *(const float4*)(g2ad + c0);
    #pragma unroll
    for (int i = 0; i < 4; ++i) {
        int n = node0 + m0 + i;
        float vs = acc[i][0] * ga.x + acc[i][1] * ga.y + acc[i][2] * ga.z + acc[i][3] * ga.w;
        float vd = acc[i][0] * gd.x + acc[i][1] * gd.y + acc[i][2] * gd.z + acc[i][3] * gd.w;
        vs += __shfl_xor(vs, 1); vs += __shfl_xor(vs, 2);
        vd += __shfl_xor(vd, 1); vd += __shfl_xor(vd, 2);
        if (n < N_NODES) {
            ushort4 hv;
            hv.x = f2bf(acc[i][0]); hv.y = f2bf(acc[i][1]);
            hv.z = f2bf(acc[i][2]); hv.w = f2bf(acc[i][3]);
            *(ushort4*)(h2 + (size_t)n * 64 + c0) = hv;
            if ((lc & 3) == 0) {
                int hh = lc >> 2;
                as2[n * 4 + hh] = vs;
                ad2[n * 4 + hh] = vd;
            }
        }
    }
}

// ---------------- GAT2 aggregate: dual-edge bf16 gather ----------------
__global__ __launch_bounds__(256) void aggregate2_kernel(
    const int* __restrict__ rowbeg, const int* __restrict__ degarr, const int* __restrict__ csr_src,
    const float* __restrict__ as, const float* __restrict__ ad,
    const unsigned short* __restrict__ h, float* __restrict__ out) {
    int wslot = threadIdx.x >> 6;
    int lane  = threadIdx.x & 63;
    int half  = lane >> 5;
    int c2    = (lane & 31) * 2;
    int head  = c2 >> 4;
    int n = blockIdx.x * 4 + wslot;
    __shared__ int    ls[4][64];
    __shared__ float4 lp4[4][64];
    if (n >= N_NODES) return;
    int base = rowbeg[n];
    int deg  = degarr[n];
    float4 add = *(const float4*)(ad + n * 4);

    float4 l = make_float4(0.f, 0.f, 0.f, 0.f);
    float a0 = 0.f, a1 = 0.f;
    for (int c0 = 0; c0 < deg; c0 += 64) {
        int j = c0 + lane;
        int s = 0;
        float4 p = make_float4(0.f, 0.f, 0.f, 0.f);
        if (j < deg) {
            s = csr_src[base + j];
            float4 a = *(const float4*)(as + s * 4);
            p.x = __expf(lrelu(a.x + add.x));
            p.y = __expf(lrelu(a.y + add.y));
            p.z = __expf(lrelu(a.z + add.z));
            p.w = __expf(lrelu(a.w + add.w));
        }
        ls[wslot][lane] = s;
        lp4[wslot][lane] = p;
        float4 t = p;
        #pragma unroll
        for (int off = 32; off > 0; off >>= 1) {
            t.x += __shfl_xor(t.x, off);
            t.y += __shfl_xor(t.y, off);
            t.z += __shfl_xor(t.z, off);
            t.w += __shfl_xor(t.w, off);
        }
        l.x += t.x; l.y += t.y; l.z += t.z; l.w += t.w;
        int cnt = min(64, deg - c0);
        const int*   lsw = ls[wslot];
        const float* lpf = (const float*)lp4[wslot];
        int j2 = 0;
        for (; j2 + 16 <= cnt; j2 += 16) {
            unsigned int raw[8];
            #pragma unroll
            for (int uu = 0; uu < 8; ++uu) {
                int e = j2 + 2 * uu + half;
                raw[uu] = *(const unsigned int*)(h + (size_t)lsw[e] * 64 + c2);
            }
            #pragma unroll
            for (int uu = 0; uu < 8; ++uu) {
                float pj = lpf[(j2 + 2 * uu + half) * 4 + head];
                a0 += pj * bf2f((unsigned short)(raw[uu] & 0xFFFFu));
                a1 += pj * bf2f((unsigned short)(raw[uu] >> 16));
            }
        }
        for (; j2 + 2 <= cnt; j2 += 2) {
            int e = j2 + half;
            unsigned int raw = *(const unsigned int*)(h + (size_t)lsw[e] * 64 + c2);
            float pj = lpf[e * 4 + head];
            a0 += pj * bf2f((unsigned short)(raw & 0xFFFFu));
            a1 += pj * bf2f((unsigned short)(raw >> 16));
        }
        if (j2 < cnt && half == 0) {
            unsigned int raw = *(const unsigned int*)(h + (size_t)lsw[j2] * 64 + c2);
            float pj = lpf[j2 * 4 + head];
            a0 += pj * bf2f((unsigned short)(raw & 0xFFFFu));
            a1 += pj * bf2f((unsigned short)(raw >> 16));
        }
    }
    a0 += __shfl_xor(a0, 32);
    a1 += __shfl_xor(a1, 32);
    float lh = (head == 0) ? l.x : (head == 1) ? l.y : (head == 2) ? l.z : l.w;
    float inv = 1.f / (lh + 1e-16f);
    if (half == 0) {
        float2 r; r.x = a0 * inv; r.y = a1 * inv;
        *(float2*)(out + (size_t)n * 64 + c2) = r;
    }
}

// ---------------- decoder: 32 nodes/block, w1 in LDS ----------------
__global__ __launch_bounds__(256) void decoder32_kernel(
    const float* __restrict__ hin, const float* __restrict__ gb,
    const float* __restrict__ w1, const float* __restrict__ b1,
    const float* __restrict__ w2, const float* __restrict__ b2, float* __restrict__ out) {
    __shared__ float s_w1[4096];
    __shared__ float s_w2[256];
    __shared__ float s_h[32][64];
    __shared__ float s_t[32][64];
    int tid = threadIdx.x;
    int node0 = blockIdx.x * 32;
    for (int i = tid; i < 4096; i += 256) s_w1[i] = w1[i];
    if (tid < 256) s_w2[tid] = w2[tid];
    for (int i = tid; i < 2048; i += 256) {
        int nn = i >> 6, k = i & 63;
        int node = node0 + nn;
        s_h[nn][k] = (node < N_NODES ? hin[(size_t)node * 64 + k] : 0.f) + gb[k];
    }
    __syncthreads();
    int c = tid & 63;
    int mg = tid >> 6;
    float b1c = b1[c];
    float acc[8];
    #pragma unroll
    for (int m = 0; m < 8; ++m) acc[m] = b1c;
    #pragma unroll 4
    for (int k = 0; k < 64; ++k) {
        float w = s_w1[k * 64 + c];
        #pragma unroll
        for (int m = 0; m < 8; ++m) acc[m] += s_h[mg * 8 + m][k] * w;
    }
    #pragma unroll
    for (int m = 0; m < 8; ++m) s_t[mg * 8 + m][c] = fmaxf(acc[m], 0.f);
    __syncthreads();
    if (tid < 128) {
        int m = tid >> 2, j = tid & 3;
        int node = node0 + m;
        if (node < N_NODES) {
            float a = b2[j];
            #pragma unroll 16
            for (int k = 0; k < 64; ++k) a += s_t[m][k] * s_w2[k * 4 + j];
            out[node * 4 + j] = a;
        }
    }
}

extern "C" void kernel_launch(void* const* d_in, const int* in_sizes, int n_in,
                              void* d_out, int out_size, void* d_ws, size_t ws_size,
                              hipStream_t stream) {
    const float* x      = (const float*)d_in[0];
    const int*   ei     = (const int*)d_in[1];
    const float* enc_w1 = (const float*)d_in[2];
    const float* enc_b1 = (const float*)d_in[3];
    const float* enc_w2 = (const float*)d_in[4];
    const float* enc_b2 = (const float*)d_in[5];
    const float* g1_w   = (const float*)d_in[6];
    const float* g1_as  = (const float*)d_in[7];
    const float* g1_ad  = (const float*)d_in[8];
    const float* g1_b   = (const float*)d_in[9];
    const float* g2_w   = (const float*)d_in[10];
    const float* g2_as  = (const float*)d_in[11];
    const float* g2_ad  = (const float*)d_in[12];
    const float* g2_b   = (const float*)d_in[13];
    const float* dec_w1 = (const float*)d_in[14];
    const float* dec_b1 = (const float*)d_in[15];
    const float* dec_w2 = (const float*)d_in[16];
    const float* dec_b2 = (const float*)d_in[17];

    const int N = N_NODES;

    // workspace layout (float offsets)
    float* ws   = (float*)d_ws;
    unsigned short* henc = (unsigned short*)ws;                   // 3.2M bf16 (1.6M floats)
    unsigned short* agg  = (unsigned short*)(ws + 3200000);       // 12.8M bf16 planar [h][n][k] (6.4M floats)
    unsigned short* h2   = (unsigned short*)(ws + 16000000);      // 3.2M bf16
    float* out2 = ws + 19200000;                                  // 3.2M fp32
    unsigned short* out1 = (unsigned short*)(ws + 22400000);      // 12.8M bf16 (6.4M floats)
    float* as1  = ws + 35200000;
    float* ad1  = as1 + 200000;
    float* as2  = ad1 + 200000;
    float* ad2  = as2 + 200000;
    float* wsf  = ad2 + 200000;              // 256
    float* wdf  = wsf + 256;                 // 256
    int*   ebuf = (int*)out1;                // NBUK*BCAP ints = 4.8 MB, dead before gemm1 writes out1
    int*   ib      = (int*)(ws + 36001024);
    int*   bcur    = ib;                     // 256
    int*   rowbeg  = ib + 256;               // 50,176
    int*   degarr  = ib + 50432;             // 50,176
    int*   csr_src = ib + 100608;            // NBUK*BCAP = 1,204,224

    // 1. zero bucket cursors + fold attention vectors
    zerofold_kernel<<<2, 256, 0, stream>>>(bcur, g1_w, g1_as, g1_ad, wsf, wdf);
    // 2. bucket-scatter edges (packed int) + encoder/alpha1 (fused; henc bf16)
    mega_kernel<<<EB_BLOCKS + ENC_BLOCKS, 256, 0, stream>>>(
        ei, bcur, ebuf, x, enc_w1, enc_b1, enc_w2, enc_b2, wsf, wdf, henc, as1, ad1);
    // 3. per-bucket CSR finalize
    bucket_csr_kernel<<<NBUK, 256, 0, stream>>>(ebuf, bcur, rowbeg, degarr, csr_src);

    // 4. GAT1 aggregate (dual-edge bf16 gather, bf16 planar out)
    aggregate1_kernel<<<(N + 3) / 4, 256, 0, stream>>>(rowbeg, degarr, csr_src, as1, ad1, henc, agg);
    // 5-6. two clean GEMMs (+ELU, +alpha2; bf16 streams)
    gemm1_kernel<<<NG64 * 4, 256, 0, stream>>>(agg, g1_w, g1_b, out1);
    gemm2_kernel<<<NG64, 256, 0, stream>>>(out1, g2_w, g2_as, g2_ad, h2, as2, ad2);

    // 7. GAT2 aggregate (dual-edge bf16 gather)
    aggregate2_kernel<<<(N + 3) / 4, 256, 0, stream>>>(rowbeg, degarr, csr_src, as2, ad2, h2, out2);

    // 8. decoder
    decoder32_kernel<<<(N + 31) / 32, 256, 0, stream>>>(out2, g2_b, dec_w1, dec_b1, dec_w2, dec_b2, (float*)d_out);
}

// Round 14
// 293.653 us; speedup vs baseline: 1.0863x; 1.0863x over previous
//
#include <hip/hip_runtime.h>
#include <hip/hip_bf16.h>

#define N_NODES 50000
#define N_EDGES 800000
#define ET_EDGES 850000   // + self loops
#define HEADS 4
#define NG64 782          // ceil(N_NODES/64)
#define ENC_BLOCKS 1563   // ceil(N_NODES/32)

// bucketed CSR build
#define BSHIFT 8
#define NBUK 196          // ceil(50000/256)
#define BCAP 6144         // max edges/bucket
#define EB_PER_BLOCK 4096
#define EB_BLOCKS 208     // 208*4096 >= 850000

__device__ __forceinline__ float lrelu(float v) { return v > 0.f ? v : 0.2f * v; }

// bf16 round-to-nearest-even pack/unpack
__device__ __forceinline__ unsigned short f2bf(float f) {
    unsigned int u = __float_as_uint(f);
    u = (u + 0x7FFFu + ((u >> 16) & 1u)) >> 16;
    return (unsigned short)u;
}
__device__ __forceinline__ float bf2f(unsigned short h) {
    return __uint_as_float((unsigned int)h << 16);
}

__device__ __forceinline__ void edge_sd(const int* __restrict__ ei, int e, int& s, int& d) {
    if (e < N_EDGES) { s = ei[e]; d = ei[N_EDGES + e]; }
    else { s = d = e - N_EDGES; }
}

// ---------------- zero bucket cursors + fold attention vectors ----------------
__global__ __launch_bounds__(256) void zerofold_kernel(
    int* __restrict__ bcur,
    const float* __restrict__ g1w, const float* __restrict__ g1as, const float* __restrict__ g1ad,
    float* __restrict__ wsf, float* __restrict__ wdf) {
    if (blockIdx.x == 0) {
        if (threadIdx.x < NBUK) bcur[threadIdx.x] = 0;
    } else {
        int tid = threadIdx.x;       // tid = h*64+k
        int h = tid >> 6, k = tid & 63;
        float as_acc = 0.f, ad_acc = 0.f;
        #pragma unroll 8
        for (int c = 0; c < 64; ++c) {
            float w = g1w[k * 256 + h * 64 + c];
            as_acc += w * g1as[h * 64 + c];
            ad_acc += w * g1ad[h * 64 + c];
        }
        wsf[tid] = as_acc;
        wdf[tid] = ad_acc;
    }
}

// ---------------- mega: bucket-scatter edges (blocks 0..EB) + encoder/alpha1 (rest) ----------------
__global__ __launch_bounds__(256) void mega_kernel(
    const int* __restrict__ ei, int* __restrict__ bcur, int* __restrict__ ebuf,
    const float* __restrict__ x, const float* __restrict__ w1, const float* __restrict__ b1,
    const float* __restrict__ w2, const float* __restrict__ b2,
    const float* __restrict__ wsf, const float* __restrict__ wdf,
    unsigned short* __restrict__ henc, float* __restrict__ as1, float* __restrict__ ad1) {
    __shared__ union {
        struct { int es[EB_PER_BLOCK]; int ed[EB_PER_BLOCK]; int h[NBUK]; int base[NBUK]; } buk;
        struct { float w2[4096]; float t[32][64]; float xx[32][8]; float he[32][65]; float wf[8 * 65]; } enc;
    } u;
    int tid = threadIdx.x;
    if (blockIdx.x < EB_BLOCKS) {
        for (int i = tid; i < NBUK; i += 256) u.buk.h[i] = 0;
        int e0 = blockIdx.x * EB_PER_BLOCK;
        __syncthreads();
        #pragma unroll
        for (int r = 0; r < EB_PER_BLOCK / 256; ++r) {
            int i = r * 256 + tid;
            int e = e0 + i;
            if (e < ET_EDGES) {
                int s, d; edge_sd(ei, e, s, d);
                u.buk.es[i] = s;
                u.buk.ed[i] = d;
                atomicAdd(&u.buk.h[d >> BSHIFT], 1);
            } else {
                u.buk.ed[i] = -1;
            }
        }
        __syncthreads();
        for (int i = tid; i < NBUK; i += 256) {
            int c = u.buk.h[i];
            u.buk.base[i] = c ? atomicAdd(bcur + i, c) : 0;
            u.buk.h[i] = 0;   // reuse as cursor
        }
        __syncthreads();
        #pragma unroll
        for (int r = 0; r < EB_PER_BLOCK / 256; ++r) {
            int i = r * 256 + tid;
            int d = u.buk.ed[i];
            if (d >= 0) {
                int b = d >> BSHIFT;
                int off = atomicAdd(&u.buk.h[b], 1);
                ebuf[b * BCAP + u.buk.base[b] + off] = ((d & 255) << 16) | u.buk.es[i];
            }
        }
        return;
    }
    // ---- encoder + fused alpha1 (32 nodes/block) ----
    int node0 = (blockIdx.x - EB_BLOCKS) * 32;
    for (int i = tid; i < 4096; i += 256) u.enc.w2[i] = w2[i];
    for (int i = tid; i < 224; i += 256) {
        int src = node0 * 7 + i;
        u.enc.xx[i / 7][i % 7] = (src < N_NODES * 7) ? x[src] : 0.f;
    }
    for (int i = tid; i < 512; i += 256) {
        int g = i >> 6, k = i & 63;
        int h = g & 3;
        u.enc.wf[g * 65 + k] = (g < 4) ? wsf[h * 64 + k] : wdf[h * 64 + k];
    }
    int c = tid & 63;
    int mg = tid >> 6;
    float w1c[7];
    #pragma unroll
    for (int k = 0; k < 7; ++k) w1c[k] = w1[k * 64 + c];
    float b1c = b1[c];
    __syncthreads();
    #pragma unroll
    for (int m = 0; m < 8; ++m) {
        int nn = mg * 8 + m;
        float a = b1c;
        #pragma unroll
        for (int k = 0; k < 7; ++k) a += u.enc.xx[nn][k] * w1c[k];
        u.enc.t[nn][c] = fmaxf(a, 0.f);
    }
    __syncthreads();
    float acc[8];
    float b2c = b2[c];
    #pragma unroll
    for (int m = 0; m < 8; ++m) acc[m] = b2c;
    #pragma unroll 4
    for (int k = 0; k < 64; ++k) {
        float w = u.enc.w2[k * 64 + c];
        #pragma unroll
        for (int m = 0; m < 8; ++m) acc[m] += u.enc.t[mg * 8 + m][k] * w;
    }
    #pragma unroll
    for (int m = 0; m < 8; ++m) {
        int nn = mg * 8 + m;
        int node = node0 + nn;
        u.enc.he[nn][c] = acc[m];
        if (node < N_NODES) henc[node * 64 + c] = f2bf(acc[m]);
    }
    __syncthreads();
    {
        int nn = tid >> 3, r = tid & 7;
        int node = node0 + nn;
        const float* wf = u.enc.wf + r * 65;
        float sum = 0.f;
        #pragma unroll 8
        for (int k = 0; k < 64; ++k) sum += u.enc.he[nn][k] * wf[k];
        if (node < N_NODES) {
            int hh = r & 3;
            if (r < 4) as1[node * 4 + hh] = sum;
            else       ad1[node * 4 + hh] = sum;
        }
    }
}

// ---------------- per-bucket CSR finalize: 1 block = 256-node bucket ----------------
__global__ __launch_bounds__(256) void bucket_csr_kernel(
    const int* __restrict__ ebuf, const int* __restrict__ bcur,
    int* __restrict__ rowbeg, int* __restrict__ degarr, int* __restrict__ csr_src) {
    __shared__ int s_deg[256];
    __shared__ int s_cur[256];
    __shared__ int s_w[4];
    int b = blockIdx.x;
    int tid = threadIdx.x;
    s_deg[tid] = 0;
    int cnt = bcur[b];
    int base = b * BCAP;
    const int* eb = ebuf + base;
    int node0 = b << BSHIFT;
    __syncthreads();
    for (int i = tid; i < cnt; i += 256) atomicAdd(&s_deg[eb[i] >> 16], 1);
    __syncthreads();
    int v = s_deg[tid];
    int lane = tid & 63, w = tid >> 6;
    int xv = v;
    #pragma unroll
    for (int off = 1; off < 64; off <<= 1) {
        int t = __shfl_up(xv, off);
        if (lane >= off) xv += t;
    }
    if (lane == 63) s_w[w] = xv;
    __syncthreads();
    if (tid == 0) {
        int a = 0;
        #pragma unroll
        for (int j = 0; j < 4; ++j) { int t = s_w[j]; s_w[j] = a; a += t; }
    }
    __syncthreads();
    int excl = xv - v + s_w[w];
    s_cur[tid] = excl;
    int node = node0 + tid;
    if (node < N_NODES) {
        rowbeg[node] = base + excl;
        degarr[node] = v;
    }
    __syncthreads();
    for (int i = tid; i < cnt; i += 256) {
        int p = eb[i];
        int pos = atomicAdd(&s_cur[p >> 16], 1);
        csr_src[base + pos] = p & 0xFFFF;
    }
}

// ---------------- GAT1 aggregate: single-edge bf16 gather (R12 layout), bf16 planar out ----------------
__global__ __launch_bounds__(256) void aggregate1_kernel(
    const int* __restrict__ rowbeg, const int* __restrict__ degarr, const int* __restrict__ csr_src,
    const float* __restrict__ as, const float* __restrict__ ad,
    const unsigned short* __restrict__ henc, unsigned short* __restrict__ agg) {
    int wslot = threadIdx.x >> 6;
    int lane  = threadIdx.x & 63;
    int n = blockIdx.x * 4 + wslot;
    __shared__ int    ls[4][64];
    __shared__ float4 lp4[4][64];
    if (n >= N_NODES) return;
    int base = rowbeg[n];
    int deg  = degarr[n];
    float4 add = *(const float4*)(ad + n * 4);

    float4 l = make_float4(0.f, 0.f, 0.f, 0.f);
    float4 acc = make_float4(0.f, 0.f, 0.f, 0.f);
    for (int c0 = 0; c0 < deg; c0 += 64) {
        int j = c0 + lane;
        int s = 0;
        float4 p = make_float4(0.f, 0.f, 0.f, 0.f);
        if (j < deg) {
            s = csr_src[base + j];
            float4 a = *(const float4*)(as + s * 4);
            p.x = __expf(lrelu(a.x + add.x));
            p.y = __expf(lrelu(a.y + add.y));
            p.z = __expf(lrelu(a.z + add.z));
            p.w = __expf(lrelu(a.w + add.w));
        }
        ls[wslot][lane] = s;
        lp4[wslot][lane] = p;
        float4 t = p;
        #pragma unroll
        for (int off = 32; off > 0; off >>= 1) {
            t.x += __shfl_xor(t.x, off);
            t.y += __shfl_xor(t.y, off);
            t.z += __shfl_xor(t.z, off);
            t.w += __shfl_xor(t.w, off);
        }
        l.x += t.x; l.y += t.y; l.z += t.z; l.w += t.w;
        int cnt = min(64, deg - c0);
        const int*    lsw = ls[wslot];
        const float4* lpw = lp4[wslot];
        int j2 = 0;
        for (; j2 + 8 <= cnt; j2 += 8) {
            float v[8];
            #pragma unroll
            for (int u = 0; u < 8; ++u) v[u] = bf2f(henc[lsw[j2+u] * 64 + lane]);
            #pragma unroll
            for (int u = 0; u < 8; ++u) {
                float4 pj = lpw[j2+u];
                acc.x += pj.x * v[u]; acc.y += pj.y * v[u];
                acc.z += pj.z * v[u]; acc.w += pj.w * v[u];
            }
        }
        for (; j2 + 4 <= cnt; j2 += 4) {
            float v0 = bf2f(henc[lsw[j2+0] * 64 + lane]);
            float v1 = bf2f(henc[lsw[j2+1] * 64 + lane]);
            float v2 = bf2f(henc[lsw[j2+2] * 64 + lane]);
            float v3 = bf2f(henc[lsw[j2+3] * 64 + lane]);
            float4 p0 = lpw[j2+0], p1 = lpw[j2+1], p2 = lpw[j2+2], p3 = lpw[j2+3];
            acc.x += p0.x*v0 + p1.x*v1 + p2.x*v2 + p3.x*v3;
            acc.y += p0.y*v0 + p1.y*v1 + p2.y*v2 + p3.y*v3;
            acc.z += p0.z*v0 + p1.z*v1 + p2.z*v2 + p3.z*v3;
            acc.w += p0.w*v0 + p1.w*v1 + p2.w*v2 + p3.w*v3;
        }
        for (; j2 < cnt; ++j2) {
            float v = bf2f(henc[lsw[j2] * 64 + lane]);
            float4 pj = lpw[j2];
            acc.x += pj.x * v; acc.y += pj.y * v;
            acc.z += pj.z * v; acc.w += pj.w * v;
        }
    }
    size_t o = (size_t)n * 64 + lane;
    const size_t PL = (size_t)N_NODES * 64;
    agg[o]          = f2bf(acc.x / (l.x + 1e-16f));
    agg[o + PL]     = f2bf(acc.y / (l.y + 1e-16f));
    agg[o + 2 * PL] = f2bf(acc.z / (l.z + 1e-16f));
    agg[o + 3 * PL] = f2bf(acc.w / (l.w + 1e-16f));
}

// ---------------- GEMM1: out1(bf16)[n][h*64+q] = ELU(sum_k agg_bf16[h][n][k]*g1w + b) ----------------
__global__ __launch_bounds__(256, 4) void gemm1_kernel(
    const unsigned short* __restrict__ agg, const float* __restrict__ g1w, const float* __restrict__ g1b,
    unsigned short* __restrict__ out1) {
    __shared__ float s_a[64 * 68];   // [n][k], stride 68
    __shared__ float s_w[4096];      // [k][q]
    int tid = threadIdx.x;
    int h = blockIdx.x & 3;
    int node0 = (blockIdx.x >> 2) * 64;
    const unsigned short* aggp = agg + (size_t)h * N_NODES * 64;
    #pragma unroll
    for (int rep = 0; rep < 4; ++rep) {
        int f4 = rep * 256 + tid;            // 0..1023
        int n = f4 >> 4, k4 = (f4 & 15) * 4;
        int node = node0 + n;
        float4 fv = make_float4(0.f, 0.f, 0.f, 0.f);
        if (node < N_NODES) {
            ushort4 rv = *(const ushort4*)(aggp + (size_t)node * 64 + k4);
            fv.x = bf2f(rv.x); fv.y = bf2f(rv.y); fv.z = bf2f(rv.z); fv.w = bf2f(rv.w);
        }
        *(float4*)(s_a + n * 68 + k4) = fv;
        *(float4*)(s_w + f4 * 4) = *(const float4*)(g1w + n * 256 + h * 64 + k4);  // n==k, k4==q4
    }
    __syncthreads();
    int lane = tid & 63, w = tid >> 6;
    int lc = lane & 15, g = lane >> 4;
    int q0 = lc * 4;
    int m0 = (w * 4 + g) * 4;
    float acc[4][4];
    #pragma unroll
    for (int i = 0; i < 4; ++i)
        #pragma unroll
        for (int j = 0; j < 4; ++j) acc[i][j] = 0.f;
    #pragma unroll 4
    for (int k = 0; k < 64; ++k) {
        float4 wv = *(const float4*)(s_w + k * 64 + q0);
        float a0 = s_a[(m0 + 0) * 68 + k];
        float a1 = s_a[(m0 + 1) * 68 + k];
        float a2 = s_a[(m0 + 2) * 68 + k];
        float a3 = s_a[(m0 + 3) * 68 + k];
        acc[0][0] += a0 * wv.x; acc[0][1] += a0 * wv.y; acc[0][2] += a0 * wv.z; acc[0][3] += a0 * wv.w;
        acc[1][0] += a1 * wv.x; acc[1][1] += a1 * wv.y; acc[1][2] += a1 * wv.z; acc[1][3] += a1 * wv.w;
        acc[2][0] += a2 * wv.x; acc[2][1] += a2 * wv.y; acc[2][2] += a2 * wv.z; acc[2][3] += a2 * wv.w;
        acc[3][0] += a3 * wv.x; acc[3][1] += a3 * wv.y; acc[3][2] += a3 * wv.z; acc[3][3] += a3 * wv.w;
    }
    float4 bb = *(const float4*)(g1b + h * 64 + q0);
    #pragma unroll
    for (int i = 0; i < 4; ++i) {
        int node = node0 + m0 + i;
        if (node < N_NODES) {
            float t0 = acc[i][0] + bb.x; t0 = t0 > 0.f ? t0 : expm1f(t0);
            float t1 = acc[i][1] + bb.y; t1 = t1 > 0.f ? t1 : expm1f(t1);
            float t2 = acc[i][2] + bb.z; t2 = t2 > 0.f ? t2 : expm1f(t2);
            float t3 = acc[i][3] + bb.w; t3 = t3 > 0.f ? t3 : expm1f(t3);
            ushort4 ov; ov.x = f2bf(t0); ov.y = f2bf(t1); ov.z = f2bf(t2); ov.w = f2bf(t3);
            *(ushort4*)(out1 + (size_t)node * 256 + h * 64 + q0) = ov;
        }
    }
}

// ---------------- GEMM2: h2(bf16)[n][c] = sum_K out1_bf16[n][K]*g2w[K][c]; + fused alpha2 ----------------
__global__ __launch_bounds__(256, 4) void gemm2_kernel(
    const unsigned short* __restrict__ out1, const float* __restrict__ g2w,
    const float* __restrict__ g2as, const float* __restrict__ g2ad,
    unsigned short* __restrict__ h2, float* __restrict__ as2, float* __restrict__ ad2) {
    __shared__ float s_v[64 * 68];   // [n][kk], stride 68
    __shared__ float s_w[4096];      // [kk][c]
    int tid = threadIdx.x;
    int node0 = blockIdx.x * 64;
    int lane = tid & 63, w = tid >> 6;
    int lc = lane & 15, g = lane >> 4;
    int c0 = lc * 4;
    int m0 = (w * 4 + g) * 4;
    float acc[4][4];
    #pragma unroll
    for (int i = 0; i < 4; ++i)
        #pragma unroll
        for (int j = 0; j < 4; ++j) acc[i][j] = 0.f;
    for (int kc = 0; kc < 4; ++kc) {
        __syncthreads();
        #pragma unroll
        for (int rep = 0; rep < 4; ++rep) {
            int f4 = rep * 256 + tid;
            int n = f4 >> 4, k4 = (f4 & 15) * 4;
            int node = node0 + n;
            float4 fv = make_float4(0.f, 0.f, 0.f, 0.f);
            if (node < N_NODES) {
                ushort4 rv = *(const ushort4*)(out1 + (size_t)node * 256 + kc * 64 + k4);
                fv.x = bf2f(rv.x); fv.y = bf2f(rv.y); fv.z = bf2f(rv.z); fv.w = bf2f(rv.w);
            }
            *(float4*)(s_v + n * 68 + k4) = fv;
            *(float4*)(s_w + f4 * 4) = *(const float4*)(g2w + kc * 4096 + f4 * 4);
        }
        __syncthreads();
        #pragma unroll 4
        for (int kk = 0; kk < 64; ++kk) {
            float4 wv = *(const float4*)(s_w + kk * 64 + c0);
            float a0 = s_v[(m0 + 0) * 68 + kk];
            float a1 = s_v[(m0 + 1) * 68 + kk];
            float a2 = s_v[(m0 + 2) * 68 + kk];
            float a3 = s_v[(m0 + 3) * 68 + kk];
            acc[0][0] += a0 * wv.x; acc[0][1] += a0 * wv.y; acc[0][2] += a0 * wv.z; acc[0][3] += a0 * wv.w;
            acc[1][0] += a1 * wv.x; acc[1][1] += a1 * wv.y; acc[1][2] += a1 * wv.z; acc[1][3] += a1 * wv.w;
            acc[2][0] += a2 * wv.x; acc[2][1] += a2 * wv.y; acc[2][2] += a2 * wv.z; acc[2][3] += a2 * wv.w;
            acc[3][0] += a3 * wv.x; acc[3][1] += a3 * wv.y; acc[3][2] += a3 * wv.z; acc[3][3] += a3 * wv.w;
        }
    }
    float4 ga = *(const float4*)(g2as + c0);
    float4 gd = *(const float4*)(g2ad + c0);
    #pragma unroll
    for (int i = 0; i < 4; ++i) {
        int n = node0 + m0 + i;
        float vs = acc[i][0] * ga.x + acc[i][1] * ga.y + acc[i][2] * ga.z + acc[i][3] * ga.w;
        float vd = acc[i][0] * gd.x + acc[i][1] * gd.y + acc[i][2] * gd.z + acc[i][3] * gd.w;
        vs += __shfl_xor(vs, 1); vs += __shfl_xor(vs, 2);
        vd += __shfl_xor(vd, 1); vd += __shfl_xor(vd, 2);
        if (n < N_NODES) {
            ushort4 hv;
            hv.x = f2bf(acc[i][0]); hv.y = f2bf(acc[i][1]);
            hv.z = f2bf(acc[i][2]); hv.w = f2bf(acc[i][3]);
            *(ushort4*)(h2 + (size_t)n * 64 + c0) = hv;
            if ((lc & 3) == 0) {
                int hh = lc >> 2;
                as2[n * 4 + hh] = vs;
                ad2[n * 4 + hh] = vd;
            }
        }
    }
}

// ---------------- GAT2 aggregate: single-edge bf16 gather (R12 layout) ----------------
__global__ __launch_bounds__(256) void aggregate2_kernel(
    const int* __restrict__ rowbeg, const int* __restrict__ degarr, const int* __restrict__ csr_src,
    const float* __restrict__ as, const float* __restrict__ ad,
    const unsigned short* __restrict__ h, float* __restrict__ out) {
    int wslot = threadIdx.x >> 6;
    int lane  = threadIdx.x & 63;
    int n = blockIdx.x * 4 + wslot;
    __shared__ int    ls[4][64];
    __shared__ float4 lp4[4][64];
    if (n >= N_NODES) return;
    int base = rowbeg[n];
    int deg  = degarr[n];
    int head = lane >> 4;
    float4 add = *(const float4*)(ad + n * 4);

    float4 l = make_float4(0.f, 0.f, 0.f, 0.f);
    float acc = 0.f;
    for (int c0 = 0; c0 < deg; c0 += 64) {
        int j = c0 + lane;
        int s = 0;
        float4 p = make_float4(0.f, 0.f, 0.f, 0.f);
        if (j < deg) {
            s = csr_src[base + j];
            float4 a = *(const float4*)(as + s * 4);
            p.x = __expf(lrelu(a.x + add.x));
            p.y = __expf(lrelu(a.y + add.y));
            p.z = __expf(lrelu(a.z + add.z));
            p.w = __expf(lrelu(a.w + add.w));
        }
        ls[wslot][lane] = s;
        lp4[wslot][lane] = p;
        float4 t = p;
        #pragma unroll
        for (int off = 32; off > 0; off >>= 1) {
            t.x += __shfl_xor(t.x, off);
            t.y += __shfl_xor(t.y, off);
            t.z += __shfl_xor(t.z, off);
            t.w += __shfl_xor(t.w, off);
        }
        l.x += t.x; l.y += t.y; l.z += t.z; l.w += t.w;
        int cnt = min(64, deg - c0);
        const int*   lsw = ls[wslot];
        const float* lpf = (const float*)lp4[wslot];
        int j2 = 0;
        for (; j2 + 8 <= cnt; j2 += 8) {
            float v[8];
            #pragma unroll
            for (int u = 0; u < 8; ++u) v[u] = bf2f(h[lsw[j2+u] * 64 + lane]);
            #pragma unroll
            for (int u = 0; u < 8; ++u) acc += lpf[(j2+u) * 4 + head] * v[u];
        }
        for (; j2 + 4 <= cnt; j2 += 4) {
            float v0 = bf2f(h[lsw[j2+0] * 64 + lane]);
            float v1 = bf2f(h[lsw[j2+1] * 64 + lane]);
            float v2 = bf2f(h[lsw[j2+2] * 64 + lane]);
            float v3 = bf2f(h[lsw[j2+3] * 64 + lane]);
            acc += lpf[(j2+0)*4+head]*v0 + lpf[(j2+1)*4+head]*v1
                 + lpf[(j2+2)*4+head]*v2 + lpf[(j2+3)*4+head]*v3;
        }
        for (; j2 < cnt; ++j2) {
            acc += lpf[j2 * 4 + head] * bf2f(h[lsw[j2] * 64 + lane]);
        }
    }
    float lh = (head == 0) ? l.x : (head == 1) ? l.y : (head == 2) ? l.z : l.w;
    out[(size_t)n * 64 + lane] = acc / (lh + 1e-16f);
}

// ---------------- decoder: 32 nodes/block, w1 in LDS ----------------
__global__ __launch_bounds__(256) void decoder32_kernel(
    const float* __restrict__ hin, const float* __restrict__ gb,
    const float* __restrict__ w1, const float* __restrict__ b1,
    const float* __restrict__ w2, const float* __restrict__ b2, float* __restrict__ out) {
    __shared__ float s_w1[4096];
    __shared__ float s_w2[256];
    __shared__ float s_h[32][64];
    __shared__ float s_t[32][64];
    int tid = threadIdx.x;
    int node0 = blockIdx.x * 32;
    for (int i = tid; i < 4096; i += 256) s_w1[i] = w1[i];
    if (tid < 256) s_w2[tid] = w2[tid];
    for (int i = tid; i < 2048; i += 256) {
        int nn = i >> 6, k = i & 63;
        int node = node0 + nn;
        s_h[nn][k] = (node < N_NODES ? hin[(size_t)node * 64 + k] : 0.f) + gb[k];
    }
    __syncthreads();
    int c = tid & 63;
    int mg = tid >> 6;
    float b1c = b1[c];
    float acc[8];
    #pragma unroll
    for (int m = 0; m < 8; ++m) acc[m] = b1c;
    #pragma unroll 4
    for (int k = 0; k < 64; ++k) {
        float w = s_w1[k * 64 + c];
        #pragma unroll
        for (int m = 0; m < 8; ++m) acc[m] += s_h[mg * 8 + m][k] * w;
    }
    #pragma unroll
    for (int m = 0; m < 8; ++m) s_t[mg * 8 + m][c] = fmaxf(acc[m], 0.f);
    __syncthreads();
    if (tid < 128) {
        int m = tid >> 2, j = tid & 3;
        int node = node0 + m;
        if (node < N_NODES) {
            float a = b2[j];
            #pragma unroll 16
            for (int k = 0; k < 64; ++k) a += s_t[m][k] * s_w2[k * 4 + j];
            out[node * 4 + j] = a;
        }
    }
}

extern "C" void kernel_launch(void* const* d_in, const int* in_sizes, int n_in,
                              void* d_out, int out_size, void* d_ws, size_t ws_size,
                              hipStream_t stream) {
    const float* x      = (const float*)d_in[0];
    const int*   ei     = (const int*)d_in[1];
    const float* enc_w1 = (const float*)d_in[2];
    const float* enc_b1 = (const float*)d_in[3];
    const float* enc_w2 = (const float*)d_in[4];
    const float* enc_b2 = (const float*)d_in[5];
    const float* g1_w   = (const float*)d_in[6];
    const float* g1_as  = (const float*)d_in[7];
    const float* g1_ad  = (const float*)d_in[8];
    const float* g1_b   = (const float*)d_in[9];
    const float* g2_w   = (const float*)d_in[10];
    const float* g2_as  = (const float*)d_in[11];
    const float* g2_ad  = (const float*)d_in[12];
    const float* g2_b   = (const float*)d_in[13];
    const float* dec_w1 = (const float*)d_in[14];
    const float* dec_b1 = (const float*)d_in[15];
    const float* dec_w2 = (const float*)d_in[16];
    const float* dec_b2 = (const float*)d_in[17];

    const int N = N_NODES;

    // workspace layout (float offsets)
    float* ws   = (float*)d_ws;
    unsigned short* henc = (unsigned short*)ws;                   // 3.2M bf16
    unsigned short* agg  = (unsigned short*)(ws + 3200000);       // 12.8M bf16 planar [h][n][k]
    unsigned short* h2   = (unsigned short*)(ws + 16000000);      // 3.2M bf16
    float* out2 = ws + 19200000;                                  // 3.2M fp32
    unsigned short* out1 = (unsigned short*)(ws + 22400000);      // 12.8M bf16
    float* as1  = ws + 35200000;
    float* ad1  = as1 + 200000;
    float* as2  = ad1 + 200000;
    float* ad2  = as2 + 200000;
    float* wsf  = ad2 + 200000;              // 256
    float* wdf  = wsf + 256;                 // 256
    int*   ebuf = (int*)out1;                // NBUK*BCAP ints = 4.8 MB, dead before gemm1 writes out1
    int*   ib      = (int*)(ws + 36001024);
    int*   bcur    = ib;                     // 256
    int*   rowbeg  = ib + 256;               // 50,176
    int*   degarr  = ib + 50432;             // 50,176
    int*   csr_src = ib + 100608;            // NBUK*BCAP = 1,204,224

    // 1. zero bucket cursors + fold attention vectors
    zerofold_kernel<<<2, 256, 0, stream>>>(bcur, g1_w, g1_as, g1_ad, wsf, wdf);
    // 2. bucket-scatter edges (packed int) + encoder/alpha1 (fused; henc bf16)
    mega_kernel<<<EB_BLOCKS + ENC_BLOCKS, 256, 0, stream>>>(
        ei, bcur, ebuf, x, enc_w1, enc_b1, enc_w2, enc_b2, wsf, wdf, henc, as1, ad1);
    // 3. per-bucket CSR finalize
    bucket_csr_kernel<<<NBUK, 256, 0, stream>>>(ebuf, bcur, rowbeg, degarr, csr_src);

    // 4. GAT1 aggregate (single-edge bf16 gather, bf16 planar out)
    aggregate1_kernel<<<(N + 3) / 4, 256, 0, stream>>>(rowbeg, degarr, csr_src, as1, ad1, henc, agg);
    // 5-6. two clean GEMMs (+ELU, +alpha2; bf16 streams)
    gemm1_kernel<<<NG64 * 4, 256, 0, stream>>>(agg, g1_w, g1_b, out1);
    gemm2_kernel<<<NG64, 256, 0, stream>>>(out1, g2_w, g2_as, g2_ad, h2, as2, ad2);

    // 7. GAT2 aggregate (single-edge bf16 gather)
    aggregate2_kernel<<<(N + 3) / 4, 256, 0, stream>>>(rowbeg, degarr, csr_src, as2, ad2, h2, out2);

    // 8. decoder
    decoder32_kernel<<<(N + 31) / 32, 256, 0, stream>>>(out2, g2_b, dec_w1, dec_b1, dec_w2, dec_b2, (float*)d_out);
}